// Round 12
// baseline (2642.172 us; speedup 1.0000x reference)
//
#include <hip/hip_runtime.h>
#include <hip/hip_bf16.h>

#define HH 128     // hidden
#define G4 512     // 4*H
#define TT 256     // encoder timesteps
#define BB 512     // batch
#define NPRED 50   // decoder steps

typedef unsigned short u16;
typedef unsigned int u32;
typedef _Float16 h2_t __attribute__((ext_vector_type(2)));

__device__ __forceinline__ float sigm(float x) { return 1.0f / (1.0f + __expf(-x)); }
__device__ __forceinline__ float tanhf_(float x) { return 1.0f - 2.0f / (__expf(2.0f * x) + 1.0f); }
__device__ __forceinline__ float bf2f(u16 u) { return __uint_as_float(((u32)u) << 16); }
__device__ __forceinline__ u16 f2bf(float f) {
    u32 x = __float_as_uint(f);
    u32 r = (x + 0x7fffu + ((x >> 16) & 1u)) >> 16;   // RTNE
    return (u16)r;
}
__device__ __forceinline__ u32 pkh2(float a, float b) {
    u16 lo = __builtin_bit_cast(u16, (_Float16)a);
    u16 hi = __builtin_bit_cast(u16, (_Float16)b);
    return (u32)lo | ((u32)hi << 16);
}
__device__ __forceinline__ h2_t u2h(u32 u) { return __builtin_bit_cast(h2_t, u); }
__device__ __forceinline__ u16 f2h(float f) { return __builtin_bit_cast(u16, (_Float16)f); }

#if defined(__has_builtin)
#if __has_builtin(__builtin_amdgcn_fdot2)
#define HAVE_FDOT2 1
#endif
#endif
#ifdef HAVE_FDOT2
#define FDOT2(w, v, acc) __builtin_amdgcn_fdot2((w), (v), (acc), false)
#else
__device__ __forceinline__ float FDOT2(h2_t a, h2_t b, float c) {
    return c + (float)a.x * (float)b.x + (float)a.y * (float)b.y;
}
#endif

// ---------------------------------------------------------------------------
// Encoder layer 0 (unchanged — measured: VGPR 48, 0 bank conflicts).
// ---------------------------------------------------------------------------
__global__ void __launch_bounds__(1024) k_scan0(
    const float* __restrict__ x, const float* __restrict__ wih,
    const float* __restrict__ whh, const float* __restrict__ bih,
    const float* __restrict__ bhh, u16* __restrict__ ys,
    float* __restrict__ hst, float* __restrict__ cst)
{
    const int tid = threadIdx.x;
    const int row = tid >> 1, half = tid & 1, base = half * 64;
    const int b0 = blockIdx.x * 2;
    __shared__ __align__(16) u16  h_h[2][HH];    // f16 hidden state
    __shared__ __align__(16) float z_s[2][G4];
    __shared__ float x_s[2][4];

    u32 wph[32];   // whh[row][base..base+64) as 32 f16-pairs
    {
        const float2* wrow = reinterpret_cast<const float2*>(whh + (size_t)row * HH + base);
#pragma unroll
        for (int k2 = 0; k2 < 32; k2++) {
            float2 v = wrow[k2];
            wph[k2] = pkh2(v.x, v.y);
        }
    }
    float wi0 = 0.f, wi1 = 0.f, wi2 = 0.f, wi3 = 0.f, bias = 0.f;
    if (half == 0) {
        wi0 = wih[row * 4]; wi1 = wih[row * 4 + 1]; wi2 = wih[row * 4 + 2]; wi3 = wih[row * 4 + 3];
        bias = bih[row] + bhh[row];
    }
    const int bb = tid >> 7, jh = tid & 127;   // eltwise roles (tid < 256)
    float creg = 0.f, hreg = 0.f;

    if (tid < 256) h_h[bb][jh] = 0;
    if (tid < 8) x_s[tid >> 2][tid & 3] = x[(size_t)(b0 + (tid >> 2)) * TT * 4 + (tid & 3)];
    __syncthreads();

    for (int t = 0; t < TT; t++) {
        float xnext = 0.f;
        if (tid < 8 && t + 1 < TT)
            xnext = x[(size_t)(b0 + (tid >> 2)) * TT * 4 + (size_t)(t + 1) * 4 + (tid & 3)];

        float a0 = 0.f, a1 = 0.f;
        if (half == 0) {
            a0 = bias + wi0 * x_s[0][0] + wi1 * x_s[0][1] + wi2 * x_s[0][2] + wi3 * x_s[0][3];
            a1 = bias + wi0 * x_s[1][0] + wi1 * x_s[1][1] + wi2 * x_s[1][2] + wi3 * x_s[1][3];
        }
#pragma unroll
        for (int q = 0; q < 8; q++) {
            uint4 hq0 = *reinterpret_cast<const uint4*>(
                reinterpret_cast<const char*>(h_h[0]) + base * 2 + q * 16);
            uint4 hq1 = *reinterpret_cast<const uint4*>(
                reinterpret_cast<const char*>(h_h[1]) + base * 2 + q * 16);
            u32 w0 = wph[4 * q], w1 = wph[4 * q + 1], w2 = wph[4 * q + 2], w3 = wph[4 * q + 3];
            a0 = FDOT2(u2h(w0), u2h(hq0.x), a0);
            a0 = FDOT2(u2h(w1), u2h(hq0.y), a0);
            a0 = FDOT2(u2h(w2), u2h(hq0.z), a0);
            a0 = FDOT2(u2h(w3), u2h(hq0.w), a0);
            a1 = FDOT2(u2h(w0), u2h(hq1.x), a1);
            a1 = FDOT2(u2h(w1), u2h(hq1.y), a1);
            a1 = FDOT2(u2h(w2), u2h(hq1.z), a1);
            a1 = FDOT2(u2h(w3), u2h(hq1.w), a1);
        }
        a0 += __shfl_xor(a0, 1);
        a1 += __shfl_xor(a1, 1);
        if (half == 0) { z_s[0][row] = a0; z_s[1][row] = a1; }
        __syncthreads();

        if (tid < 256) {
            float zi = z_s[bb][jh], zf = z_s[bb][HH + jh], zg = z_s[bb][2 * HH + jh], zo = z_s[bb][3 * HH + jh];
            float c = sigm(zf) * creg + sigm(zi) * tanhf_(zg);
            float h = sigm(zo) * tanhf_(c);
            creg = c; hreg = h;
            h_h[bb][jh] = f2h(h);
            ys[((size_t)(b0 + bb) * TT + t) * HH + jh] = f2bf(h);
        }
        if (tid < 8 && t + 1 < TT) x_s[tid >> 2][tid & 3] = xnext;
        __syncthreads();
    }
    if (tid < 256) {
        hst[(size_t)(b0 + bb) * HH + jh] = hreg;
        cst[(size_t)(b0 + bb) * HH + jh] = creg;
    }
}

// ---------------------------------------------------------------------------
// Encoder layers 1,2 (unchanged — measured-good).
// ---------------------------------------------------------------------------
__global__ void __launch_bounds__(1024) k_scanL(
    const float* __restrict__ wih, const float* __restrict__ whh,
    const float* __restrict__ bih, const float* __restrict__ bhh,
    u16* __restrict__ ys, int write_ys,
    float* __restrict__ hst, float* __restrict__ cst)
{
    const int tid = threadIdx.x;
    const int row = tid >> 1, half = tid & 1, base = half * 64;
    const int b0 = blockIdx.x * 2;
    __shared__ __align__(16) u16  h_h[2][HH];    // f16 hidden
    __shared__ __align__(16) u16  y_h[2][HH];    // f16 layer input
    __shared__ __align__(16) float z_s[2][G4];

    u32 wph[32], wpi[32];
    {
        const float2* wrow = reinterpret_cast<const float2*>(whh + (size_t)row * HH + base);
        const float2* irow = reinterpret_cast<const float2*>(wih + (size_t)row * HH + base);
#pragma unroll
        for (int k2 = 0; k2 < 32; k2++) {
            float2 v = wrow[k2]; wph[k2] = pkh2(v.x, v.y);
            float2 w = irow[k2]; wpi[k2] = pkh2(w.x, w.y);
        }
    }
    const float bias = bih[row] + bhh[row];   // used by half==0 at write
    const int bb = tid >> 7, jh = tid & 127;
    float creg = 0.f, hreg = 0.f;

    if (tid < 256) {
        h_h[bb][jh] = 0;
        y_h[bb][jh] = f2h(bf2f(ys[((size_t)(b0 + bb) * TT) * HH + jh]));
    }
    __syncthreads();

    for (int t = 0; t < TT; t++) {
        u16 ynext = 0;
        if (tid < 256 && t + 1 < TT)
            ynext = ys[((size_t)(b0 + bb) * TT + (t + 1)) * HH + jh];

        float a0 = 0.f, a1 = 0.f;
#pragma unroll
        for (int q = 0; q < 8; q++) {
            uint4 hq0 = *reinterpret_cast<const uint4*>(
                reinterpret_cast<const char*>(h_h[0]) + base * 2 + q * 16);
            uint4 hq1 = *reinterpret_cast<const uint4*>(
                reinterpret_cast<const char*>(h_h[1]) + base * 2 + q * 16);
            uint4 yq0 = *reinterpret_cast<const uint4*>(
                reinterpret_cast<const char*>(y_h[0]) + base * 2 + q * 16);
            uint4 yq1 = *reinterpret_cast<const uint4*>(
                reinterpret_cast<const char*>(y_h[1]) + base * 2 + q * 16);
            u32 h0 = wph[4 * q], h1 = wph[4 * q + 1], h2 = wph[4 * q + 2], h3 = wph[4 * q + 3];
            u32 i0 = wpi[4 * q], i1 = wpi[4 * q + 1], i2 = wpi[4 * q + 2], i3 = wpi[4 * q + 3];
            a0 = FDOT2(u2h(h0), u2h(hq0.x), a0);
            a0 = FDOT2(u2h(h1), u2h(hq0.y), a0);
            a0 = FDOT2(u2h(h2), u2h(hq0.z), a0);
            a0 = FDOT2(u2h(h3), u2h(hq0.w), a0);
            a0 = FDOT2(u2h(i0), u2h(yq0.x), a0);
            a0 = FDOT2(u2h(i1), u2h(yq0.y), a0);
            a0 = FDOT2(u2h(i2), u2h(yq0.z), a0);
            a0 = FDOT2(u2h(i3), u2h(yq0.w), a0);
            a1 = FDOT2(u2h(h0), u2h(hq1.x), a1);
            a1 = FDOT2(u2h(h1), u2h(hq1.y), a1);
            a1 = FDOT2(u2h(h2), u2h(hq1.z), a1);
            a1 = FDOT2(u2h(h3), u2h(hq1.w), a1);
            a1 = FDOT2(u2h(i0), u2h(yq1.x), a1);
            a1 = FDOT2(u2h(i1), u2h(yq1.y), a1);
            a1 = FDOT2(u2h(i2), u2h(yq1.z), a1);
            a1 = FDOT2(u2h(i3), u2h(yq1.w), a1);
        }
        a0 += __shfl_xor(a0, 1);
        a1 += __shfl_xor(a1, 1);
        if (half == 0) { z_s[0][row] = a0 + bias; z_s[1][row] = a1 + bias; }
        __syncthreads();

        if (tid < 256) {
            float zi = z_s[bb][jh], zf = z_s[bb][HH + jh], zg = z_s[bb][2 * HH + jh], zo = z_s[bb][3 * HH + jh];
            float c = sigm(zf) * creg + sigm(zi) * tanhf_(zg);
            float h = sigm(zo) * tanhf_(c);
            creg = c; hreg = h;
            h_h[bb][jh] = f2h(h);
            if (write_ys) ys[((size_t)(b0 + bb) * TT + t) * HH + jh] = f2bf(h);
            if (t + 1 < TT) y_h[bb][jh] = f2h(bf2f(ynext));
        }
        __syncthreads();
    }
    if (tid < 256) {
        hst[(size_t)(b0 + bb) * HH + jh] = hreg;
        cst[(size_t)(b0 + bb) * HH + jh] = creg;
    }
}

// ---------------------------------------------------------------------------
// Pack (unchanged — layout keyed to tid/p/m only):
// o = ((m*4+p)*1024 + t)*8 + u ; row = p*128 + (t>>3); col = (t&7)*16 + 2u.
// ---------------------------------------------------------------------------
__global__ void __launch_bounds__(256) k_pack(
    const float* __restrict__ w0h, const float* __restrict__ w1i,
    const float* __restrict__ w1h, const float* __restrict__ w2i,
    const float* __restrict__ w2h, u32* __restrict__ wpk)
{
    int o = blockIdx.x * 256 + threadIdx.x;      // 0 .. 163839
    int m = o >> 15;            // 32768 u32 per matrix
    int rem = o & 32767;
    int p = rem >> 13;          // 8192 u32 per gate-block
    int rem2 = rem & 8191;
    int t = rem2 >> 3;          // thread 0..1023
    int u = rem2 & 7;           // u32 within thread's 2 uint4
    int row = p * 128 + (t >> 3);
    int col = (t & 7) * 16 + 2 * u;
    const float* src = (m == 0) ? w0h : (m == 1) ? w1i : (m == 2) ? w1h : (m == 3) ? w2i : w2h;
    float v0 = src[row * 128 + col], v1 = src[row * 128 + col + 1];
    wpk[o] = pkh2(v0, v1);
}

// ---------------------------------------------------------------------------
// Decoder: 50 steps x 3 layers. 1024 thr, 4 batch, grid 128.
// Round-11 evidence: decode time == TCC-miss bytes / ~2.1 TB/s (miss ~30% of
// the per-block 640 KB/step weight stream at ALL grid sizes) -> demand is the
// lever: B=4/grid 128 halves demand vs round 11. Round 10 (same shape) was
// latency-bound (1.18 TB/s): fixed here by (a) hoisting h-chunks across the
// p-loop (LDS b128 reads 160 -> 40/thread/step), (b) per-matrix passes with
// same-thread z_s accumulation (keeps hoisted set at 8 uint4 = 32 VGPR),
// (c) p->p+1 weight prefetch. ~85 VGPR, no spill.
// ---------------------------------------------------------------------------
#define DOT8(A, W0, W1, V0, V1)                      \
    A = FDOT2(u2h((W0).x), u2h((V0).x), A);          \
    A = FDOT2(u2h((W0).y), u2h((V0).y), A);          \
    A = FDOT2(u2h((W0).z), u2h((V0).z), A);          \
    A = FDOT2(u2h((W0).w), u2h((V0).w), A);          \
    A = FDOT2(u2h((W1).x), u2h((V1).x), A);          \
    A = FDOT2(u2h((W1).y), u2h((V1).y), A);          \
    A = FDOT2(u2h((W1).z), u2h((V1).z), A);          \
    A = FDOT2(u2h((W1).w), u2h((V1).w), A);

#define R3(A) { A += __shfl_xor(A, 1); A += __shfl_xor(A, 2); A += __shfl_xor(A, 4); }

__global__ void __launch_bounds__(1024) k_decode(
    const float* __restrict__ x,
    const float* __restrict__ w0i,
    const float* __restrict__ b0i, const float* __restrict__ b0h,
    const float* __restrict__ b1i, const float* __restrict__ b1h,
    const float* __restrict__ b2i, const float* __restrict__ b2h,
    const float* __restrict__ fcw, const float* __restrict__ fcb,
    const float* __restrict__ hst, const float* __restrict__ cst,
    const uint4* __restrict__ wpk,
    float* __restrict__ out)
{
    const int tid = threadIdx.x;
    const int b0 = blockIdx.x * 4;
    const int r = tid >> 3;        // output row slot 0..127
    const int g = tid & 7;         // 16-col group
    __shared__ __align__(16) u16  h_h[3][4][HH];     // f16 hidden states
    __shared__ __align__(16) float h2f_s[4][HH];     // f32 copy of layer-2 h (fc)
    __shared__ __align__(16) float z_s[4][G4];
    __shared__ __align__(16) float in0_s[4][4];
    __shared__ __align__(16) float fcw_s[HH];
    __shared__ __align__(16) float bs_lds[3][G4];    // bih+bhh per layer
    __shared__ __align__(16) float wi0_lds[G4][4];   // layer-0 wih rows

    const int bb = tid >> 7, jh = tid & 127;         // eltwise roles (tid<512)
    float c0 = 0.f, c1 = 0.f, c2 = 0.f;
    if (tid < 512) {
        c0 = cst[((size_t)0 * BB + b0 + bb) * HH + jh];
        c1 = cst[((size_t)1 * BB + b0 + bb) * HH + jh];
        c2 = cst[((size_t)2 * BB + b0 + bb) * HH + jh];
        h_h[0][bb][jh] = f2h(hst[((size_t)0 * BB + b0 + bb) * HH + jh]);
        h_h[1][bb][jh] = f2h(hst[((size_t)1 * BB + b0 + bb) * HH + jh]);
        h_h[2][bb][jh] = f2h(hst[((size_t)2 * BB + b0 + bb) * HH + jh]);
        bs_lds[0][tid] = b0i[tid] + b0h[tid];
        bs_lds[1][tid] = b1i[tid] + b1h[tid];
        bs_lds[2][tid] = b2i[tid] + b2h[tid];
        float4 wv = reinterpret_cast<const float4*>(w0i)[tid];
        wi0_lds[tid][0] = wv.x; wi0_lds[tid][1] = wv.y;
        wi0_lds[tid][2] = wv.z; wi0_lds[tid][3] = wv.w;
    }
    if (tid < HH) fcw_s[tid] = fcw[tid];
    if (tid < 16) in0_s[tid >> 2][tid & 3] = x[(size_t)(b0 + (tid >> 2)) * TT * 4 + (size_t)(TT - 1) * 4 + (tid & 3)];
    const float fcbv = fcb[0];
    __syncthreads();

#define VEC_CHUNK(l, b, q) (*reinterpret_cast<const uint4*>( \
        reinterpret_cast<const char*>(&h_h[l][b][0]) + g * 32 + (q) * 16))

    for (int s = 0; s < NPRED; s++) {
        // ============ L0: z = w0h*h0 + bs0 + w0i*in0 (pass m=0) ============
        {
            uint4 v0a = VEC_CHUNK(0, 0, 0), v0b = VEC_CHUNK(0, 0, 1);
            uint4 v1a = VEC_CHUNK(0, 1, 0), v1b = VEC_CHUNK(0, 1, 1);
            uint4 v2a = VEC_CHUNK(0, 2, 0), v2b = VEC_CHUNK(0, 2, 1);
            uint4 v3a = VEC_CHUNK(0, 3, 0), v3b = VEC_CHUNK(0, 3, 1);
            const uint4* wc = wpk + (((0 * 4 + 0) * 1024 + tid) << 1);
            uint4 wA0 = wc[0], wA1 = wc[1];
#pragma unroll
            for (int p = 0; p < 4; p++) {
                uint4 wB0, wB1;
                if (p < 3) { wB0 = wc[(p + 1) * 2048]; wB1 = wc[(p + 1) * 2048 + 1]; }
                float a0 = 0.f, a1 = 0.f, a2 = 0.f, a3 = 0.f;
                DOT8(a0, wA0, wA1, v0a, v0b);
                DOT8(a1, wA0, wA1, v1a, v1b);
                DOT8(a2, wA0, wA1, v2a, v2b);
                DOT8(a3, wA0, wA1, v3a, v3b);
                R3(a0); R3(a1); R3(a2); R3(a3);
                if (g == 0) {
                    int row = p * 128 + r;
                    float w0 = wi0_lds[row][0], w1 = wi0_lds[row][1];
                    float w2 = wi0_lds[row][2], w3 = wi0_lds[row][3];
                    float bs = bs_lds[0][row];
                    z_s[0][row] = a0 + bs + w0 * in0_s[0][0] + w1 * in0_s[0][1] + w2 * in0_s[0][2] + w3 * in0_s[0][3];
                    z_s[1][row] = a1 + bs + w0 * in0_s[1][0] + w1 * in0_s[1][1] + w2 * in0_s[1][2] + w3 * in0_s[1][3];
                    z_s[2][row] = a2 + bs + w0 * in0_s[2][0] + w1 * in0_s[2][1] + w2 * in0_s[2][2] + w3 * in0_s[2][3];
                    z_s[3][row] = a3 + bs + w0 * in0_s[3][0] + w1 * in0_s[3][1] + w2 * in0_s[3][2] + w3 * in0_s[3][3];
                }
                wA0 = wB0; wA1 = wB1;
            }
        }
        __syncthreads();
        if (tid < 512) {
            float zi = z_s[bb][jh], zf = z_s[bb][HH + jh], zg = z_s[bb][2 * HH + jh], zo = z_s[bb][3 * HH + jh];
            c0 = sigm(zf) * c0 + sigm(zi) * tanhf_(zg);
            h_h[0][bb][jh] = f2h(sigm(zo) * tanhf_(c0));
        }
        __syncthreads();
        // ============ L1: pass m=1 (w1i*h0, init bs1), pass m=2 (w1h*h1, acc) ============
        {
            uint4 v0a = VEC_CHUNK(0, 0, 0), v0b = VEC_CHUNK(0, 0, 1);
            uint4 v1a = VEC_CHUNK(0, 1, 0), v1b = VEC_CHUNK(0, 1, 1);
            uint4 v2a = VEC_CHUNK(0, 2, 0), v2b = VEC_CHUNK(0, 2, 1);
            uint4 v3a = VEC_CHUNK(0, 3, 0), v3b = VEC_CHUNK(0, 3, 1);
            const uint4* wc = wpk + (((1 * 4 + 0) * 1024 + tid) << 1);
            uint4 wA0 = wc[0], wA1 = wc[1];
#pragma unroll
            for (int p = 0; p < 4; p++) {
                uint4 wB0, wB1;
                if (p < 3) { wB0 = wc[(p + 1) * 2048]; wB1 = wc[(p + 1) * 2048 + 1]; }
                float a0 = 0.f, a1 = 0.f, a2 = 0.f, a3 = 0.f;
                DOT8(a0, wA0, wA1, v0a, v0b);
                DOT8(a1, wA0, wA1, v1a, v1b);
                DOT8(a2, wA0, wA1, v2a, v2b);
                DOT8(a3, wA0, wA1, v3a, v3b);
                R3(a0); R3(a1); R3(a2); R3(a3);
                if (g == 0) {
                    int row = p * 128 + r;
                    float bs = bs_lds[1][row];
                    z_s[0][row] = a0 + bs; z_s[1][row] = a1 + bs;
                    z_s[2][row] = a2 + bs; z_s[3][row] = a3 + bs;
                }
                wA0 = wB0; wA1 = wB1;
            }
        }
        {
            uint4 v0a = VEC_CHUNK(1, 0, 0), v0b = VEC_CHUNK(1, 0, 1);
            uint4 v1a = VEC_CHUNK(1, 1, 0), v1b = VEC_CHUNK(1, 1, 1);
            uint4 v2a = VEC_CHUNK(1, 2, 0), v2b = VEC_CHUNK(1, 2, 1);
            uint4 v3a = VEC_CHUNK(1, 3, 0), v3b = VEC_CHUNK(1, 3, 1);
            const uint4* wc = wpk + (((2 * 4 + 0) * 1024 + tid) << 1);
            uint4 wA0 = wc[0], wA1 = wc[1];
#pragma unroll
            for (int p = 0; p < 4; p++) {
                uint4 wB0, wB1;
                if (p < 3) { wB0 = wc[(p + 1) * 2048]; wB1 = wc[(p + 1) * 2048 + 1]; }
                float a0 = 0.f, a1 = 0.f, a2 = 0.f, a3 = 0.f;
                DOT8(a0, wA0, wA1, v0a, v0b);
                DOT8(a1, wA0, wA1, v1a, v1b);
                DOT8(a2, wA0, wA1, v2a, v2b);
                DOT8(a3, wA0, wA1, v3a, v3b);
                R3(a0); R3(a1); R3(a2); R3(a3);
                if (g == 0) {
                    int row = p * 128 + r;
                    z_s[0][row] += a0; z_s[1][row] += a1;
                    z_s[2][row] += a2; z_s[3][row] += a3;
                }
                wA0 = wB0; wA1 = wB1;
            }
        }
        __syncthreads();
        if (tid < 512) {
            float zi = z_s[bb][jh], zf = z_s[bb][HH + jh], zg = z_s[bb][2 * HH + jh], zo = z_s[bb][3 * HH + jh];
            c1 = sigm(zf) * c1 + sigm(zi) * tanhf_(zg);
            h_h[1][bb][jh] = f2h(sigm(zo) * tanhf_(c1));
        }
        __syncthreads();
        // ============ L2: pass m=3 (w2i*h1, init bs2), pass m=4 (w2h*h2, acc) ============
        {
            uint4 v0a = VEC_CHUNK(1, 0, 0), v0b = VEC_CHUNK(1, 0, 1);
            uint4 v1a = VEC_CHUNK(1, 1, 0), v1b = VEC_CHUNK(1, 1, 1);
            uint4 v2a = VEC_CHUNK(1, 2, 0), v2b = VEC_CHUNK(1, 2, 1);
            uint4 v3a = VEC_CHUNK(1, 3, 0), v3b = VEC_CHUNK(1, 3, 1);
            const uint4* wc = wpk + (((3 * 4 + 0) * 1024 + tid) << 1);
            uint4 wA0 = wc[0], wA1 = wc[1];
#pragma unroll
            for (int p = 0; p < 4; p++) {
                uint4 wB0, wB1;
                if (p < 3) { wB0 = wc[(p + 1) * 2048]; wB1 = wc[(p + 1) * 2048 + 1]; }
                float a0 = 0.f, a1 = 0.f, a2 = 0.f, a3 = 0.f;
                DOT8(a0, wA0, wA1, v0a, v0b);
                DOT8(a1, wA0, wA1, v1a, v1b);
                DOT8(a2, wA0, wA1, v2a, v2b);
                DOT8(a3, wA0, wA1, v3a, v3b);
                R3(a0); R3(a1); R3(a2); R3(a3);
                if (g == 0) {
                    int row = p * 128 + r;
                    float bs = bs_lds[2][row];
                    z_s[0][row] = a0 + bs; z_s[1][row] = a1 + bs;
                    z_s[2][row] = a2 + bs; z_s[3][row] = a3 + bs;
                }
                wA0 = wB0; wA1 = wB1;
            }
        }
        {
            uint4 v0a = VEC_CHUNK(2, 0, 0), v0b = VEC_CHUNK(2, 0, 1);
            uint4 v1a = VEC_CHUNK(2, 1, 0), v1b = VEC_CHUNK(2, 1, 1);
            uint4 v2a = VEC_CHUNK(2, 2, 0), v2b = VEC_CHUNK(2, 2, 1);
            uint4 v3a = VEC_CHUNK(2, 3, 0), v3b = VEC_CHUNK(2, 3, 1);
            const uint4* wc = wpk + (((4 * 4 + 0) * 1024 + tid) << 1);
            uint4 wA0 = wc[0], wA1 = wc[1];
#pragma unroll
            for (int p = 0; p < 4; p++) {
                uint4 wB0, wB1;
                if (p < 3) { wB0 = wc[(p + 1) * 2048]; wB1 = wc[(p + 1) * 2048 + 1]; }
                float a0 = 0.f, a1 = 0.f, a2 = 0.f, a3 = 0.f;
                DOT8(a0, wA0, wA1, v0a, v0b);
                DOT8(a1, wA0, wA1, v1a, v1b);
                DOT8(a2, wA0, wA1, v2a, v2b);
                DOT8(a3, wA0, wA1, v3a, v3b);
                R3(a0); R3(a1); R3(a2); R3(a3);
                if (g == 0) {
                    int row = p * 128 + r;
                    z_s[0][row] += a0; z_s[1][row] += a1;
                    z_s[2][row] += a2; z_s[3][row] += a3;
                }
                wA0 = wB0; wA1 = wB1;
            }
        }
        __syncthreads();
        if (tid < 512) {
            float zi = z_s[bb][jh], zf = z_s[bb][HH + jh], zg = z_s[bb][2 * HH + jh], zo = z_s[bb][3 * HH + jh];
            c2 = sigm(zf) * c2 + sigm(zi) * tanhf_(zg);
            float h = sigm(zo) * tanhf_(c2);
            h_h[2][bb][jh] = f2h(h);
            h2f_s[bb][jh] = h;
        }
        __syncthreads();
        // ----- fc + feedback -----
        if (tid < 256) {
            const int w = tid >> 6, lane = tid & 63;
            float p = h2f_s[w][lane] * fcw_s[lane] + h2f_s[w][lane + 64] * fcw_s[lane + 64];
#pragma unroll
            for (int off = 32; off > 0; off >>= 1) p += __shfl_down(p, off);
            if (lane == 0) {
                float pr = p + fcbv;
                out[(size_t)(b0 + w) * NPRED + s] = pr;
                in0_s[w][0] = pr;
            }
        } else if (tid < 272) {
            int q = tid - 256;            // 0..15
            int b = q >> 2, k = q & 3;
            if (k > 0) in0_s[b][k] = 0.f; // zeros_feat
        }
        __syncthreads();
    }
#undef VEC_CHUNK
}

extern "C" void kernel_launch(void* const* d_in, const int* in_sizes, int n_in,
                              void* d_out, int out_size, void* d_ws, size_t ws_size,
                              hipStream_t stream)
{
    const float* x = (const float*)d_in[0];
    const float* e0_wih = (const float*)d_in[1];
    const float* e0_whh = (const float*)d_in[2];
    const float* e0_bih = (const float*)d_in[3];
    const float* e0_bhh = (const float*)d_in[4];
    const float* e1_wih = (const float*)d_in[5];
    const float* e1_whh = (const float*)d_in[6];
    const float* e1_bih = (const float*)d_in[7];
    const float* e1_bhh = (const float*)d_in[8];
    const float* e2_wih = (const float*)d_in[9];
    const float* e2_whh = (const float*)d_in[10];
    const float* e2_bih = (const float*)d_in[11];
    const float* e2_bhh = (const float*)d_in[12];
    const float* d0_wih = (const float*)d_in[13];
    const float* d0_whh = (const float*)d_in[14];
    const float* d0_bih = (const float*)d_in[15];
    const float* d0_bhh = (const float*)d_in[16];
    const float* d1_wih = (const float*)d_in[17];
    const float* d1_whh = (const float*)d_in[18];
    const float* d1_bih = (const float*)d_in[19];
    const float* d1_bhh = (const float*)d_in[20];
    const float* d2_wih = (const float*)d_in[21];
    const float* d2_whh = (const float*)d_in[22];
    const float* d2_bih = (const float*)d_in[23];
    const float* d2_bhh = (const float*)d_in[24];
    const float* fc_w = (const float*)d_in[25];
    const float* fc_b = (const float*)d_in[26];

    // workspace layout
    u16* ys = (u16*)d_ws;                                   // B*T*H bf16 = 33.5 MB
    size_t ys_bytes = (size_t)BB * TT * HH * sizeof(u16);
    float* hst = (float*)((char*)d_ws + ys_bytes);          // 3*B*H f32
    float* cst = hst + (size_t)3 * BB * HH;                 // 3*B*H f32
    u32* wpk = (u32*)(cst + (size_t)3 * BB * HH);           // 163840 u32 = 640 KB
    const size_t BH = (size_t)BB * HH;

    k_pack<<<dim3(640), dim3(256), 0, stream>>>(d0_whh, d1_wih, d1_whh, d2_wih, d2_whh, wpk);
    k_scan0<<<dim3(256), dim3(1024), 0, stream>>>(x, e0_wih, e0_whh, e0_bih, e0_bhh,
                                                  ys, hst, cst);
    k_scanL<<<dim3(256), dim3(1024), 0, stream>>>(e1_wih, e1_whh, e1_bih, e1_bhh,
                                                  ys, 1, hst + BH, cst + BH);
    k_scanL<<<dim3(256), dim3(1024), 0, stream>>>(e2_wih, e2_whh, e2_bih, e2_bhh,
                                                  ys, 0, hst + 2 * BH, cst + 2 * BH);
    k_decode<<<dim3(128), dim3(1024), 0, stream>>>(
        x, d0_wih, d0_bih, d0_bhh, d1_bih, d1_bhh, d2_bih, d2_bhh,
        fc_w, fc_b, hst, cst, (const uint4*)wpk, (float*)d_out);
}